// Round 12
// baseline (386.244 us; speedup 1.0000x reference)
//
#include <hip/hip_runtime.h>

typedef unsigned short u16;
typedef unsigned int   u32;
typedef short bf16x8 __attribute__((ext_vector_type(8)));
typedef float f32x4  __attribute__((ext_vector_type(4)));

#define NTOK 4096   // B*S
#define SEQ  1024

__device__ __forceinline__ u16 f2bf(float f){
  union { float f; u32 u; } x; x.f = f;
  u32 r = (x.u + 0x7FFFu + ((x.u >> 16) & 1u)) >> 16;
  return (u16)r;
}
__device__ __forceinline__ float bf2f(u16 u){
  union { u32 u; float f; } x; x.u = ((u32)u) << 16; return x.f;
}
__device__ __forceinline__ void gl_lds16(const void* gp, void* lp){
  __builtin_amdgcn_global_load_lds(
      (const __attribute__((address_space(1))) u32*)gp,
      (__attribute__((address_space(3))) u32*)lp, 16, 0, 0);
}

// ---------------------------------------------------------------- fused prologue
// One launch: conv_x + conv_w_all + sqbuf zero. Region boundaries block-aligned.
__global__ __launch_bounds__(256) void conv_all(
    const float* __restrict__ x,
    const float* __restrict__ Wq, const float* __restrict__ Wk,
    const float* __restrict__ Wv, const float* __restrict__ Wo,
    const float* __restrict__ W1, const float* __restrict__ W2,
    u16* __restrict__ xs, float* __restrict__ xt,
    u16* __restrict__ wqkv, u16* __restrict__ wo_s, u16* __restrict__ w1_s, u16* __restrict__ w2_s,
    float* __restrict__ wqkv0, float* __restrict__ wo0, float* __restrict__ w10, float* __restrict__ w20,
    float* __restrict__ sqbuf)
{
  int t = blockIdx.x * 256 + threadIdx.x;
  const int QX = 1049600;                 // x quads (4100 blocks)
  const int Q1 = 262400;                  // quads per 1024x1025 weight
  const int QW = 4 * Q1 + 1049600 + 1048832;   // 3,148,032 (12297 blocks)
  if (t < QX){
    int e = t * 4;
    int r = (u32)e / 1025u;
    int c = e - r * 1025;
    float4 v = *(const float4*)(x + (size_t)e);
    const float* vp = (const float*)&v;
    #pragma unroll
    for (int k = 0; k < 4; k++){
      if (c == 0) xt[r] = vp[k];
      else xs[(size_t)r * 1024 + (c - 1)] = f2bf(vp[k]);
      if (++c == 1025){ c = 0; ++r; }
    }
    return;
  }
  t -= QX;
  if (t < QW){
    const float* W; u16* Wb; float* w0; int divr, Kin, e;
    if (t < 4 * Q1){
      int region = t / Q1; int qq = t - region * Q1;
      e = qq * 4; divr = 1025; Kin = 1024;
      if (region == 0)      { W = Wq; Wb = wqkv;             w0 = wqkv0; }
      else if (region == 1) { W = Wk; Wb = wqkv + (1 << 20); w0 = wqkv0 + 1024; }
      else if (region == 2) { W = Wv; Wb = wqkv + (2 << 20); w0 = wqkv0 + 2048; }
      else                  { W = Wo; Wb = wo_s;             w0 = wo0; }
    } else if (t < 4 * Q1 + 1049600){
      e = (t - 4 * Q1) * 4; divr = 1025; Kin = 1024; W = W1; Wb = w1_s; w0 = w10;
    } else {
      e = (t - 4 * Q1 - 1049600) * 4; divr = 4097; Kin = 4096; W = W2; Wb = w2_s; w0 = w20;
    }
    int r = (divr == 1025) ? (int)((u32)e / 1025u) : (int)((u32)e / 4097u);
    int c = e - r * divr;
    float4 v = *(const float4*)(W + (size_t)e);
    const float* vp = (const float*)&v;
    #pragma unroll
    for (int k = 0; k < 4; k++){
      if (c == 0) w0[r] = vp[k];
      else Wb[(size_t)r * Kin + (c - 1)] = f2bf(vp[k]);
      if (++c == divr){ c = 0; ++r; }
    }
    return;
  }
  t -= QW;
  if (t < 2 * NTOK) sqbuf[t] = 0.f;       // aot_sq | htv_sq zero (32 blocks)
}

// ---------------------------------------------------------------- QKV GEMM (isolated, mode-0; V written transposed)
// Q/K blocks (n0 < 2048): write qkvb + qtv/ktv time rows as before.
// V blocks (n0 >= 2048, block-uniform): write vT DIRECTLY in transposed
// layout (each thread's 4 acc rows are 4 consecutive tokens of one feature
// -> one aligned 8B store) + f2bf time row. Replaces the v_transpose kernel
// entirely (launch + 17 MB traffic); qkvb V-third is never written (attn
// reads only Q/K from qkvb, V from vT).
__global__ __launch_bounds__(256) void gemm128_qkv(
    const u16* __restrict__ A, const u16* __restrict__ Bm,
    const float* __restrict__ at, const float* __restrict__ b0,
    const float* __restrict__ bias_a, const float* __restrict__ bias_b, const float* __restrict__ bias_c,
    u16* __restrict__ Cbf,
    float* __restrict__ qtv, float* __restrict__ ktv, u16* __restrict__ vT)
{
  __shared__ u16 As[2][128 * 64];
  __shared__ u16 Bs[2][128 * 64];
  const int tid = threadIdx.x;
  const int w = tid >> 6, l = tid & 63;
  const int l15 = l & 15, q = l >> 4;
  const int m0 = blockIdx.y * 128, n0 = blockIdx.x * 128;
  const int wr = w >> 1, wc = w & 1;
  f32x4 acc[4][4] = {};

  auto stage = [&](int kt, int buf){
    #pragma unroll
    for (int half = 0; half < 2; half++){
      #pragma unroll
      for (int i = 0; i < 2; i++){
        int s = (w * 2 + i) * 64 + l;
        int row = s >> 2;
        int kc = ((s & 3) - (s >> 3)) & 3;
        gl_lds16(A  + (size_t)(m0 + row) * 1024 + kt + half * 32 + kc * 8,
                 &As[buf][half * 4096 + (w * 2 + i) * 512]);
        gl_lds16(Bm + (size_t)(n0 + row) * 1024 + kt + half * 32 + kc * 8,
                 &Bs[buf][half * 4096 + (w * 2 + i) * 512]);
      }
    }
  };
  auto compute = [&](int buf, int half){
    bf16x8 af[4], bfr[4];
    #pragma unroll
    for (int i = 0; i < 4; i++){
      int row = wr * 64 + i * 16 + l15;
      int slot = row * 4 + ((q + (row >> 1)) & 3);
      af[i] = *(const bf16x8*)&As[buf][half * 4096 + slot * 8];
    }
    #pragma unroll
    for (int j = 0; j < 4; j++){
      int row = wc * 64 + j * 16 + l15;
      int slot = row * 4 + ((q + (row >> 1)) & 3);
      bfr[j] = *(const bf16x8*)&Bs[buf][half * 4096 + slot * 8];
    }
    #pragma unroll
    for (int i = 0; i < 4; i++)
      #pragma unroll
      for (int j = 0; j < 4; j++)
        acc[i][j] = __builtin_amdgcn_mfma_f32_16x16x32_bf16(af[i], bfr[j], acc[i][j], 0, 0, 0);
  };

  stage(0, 0);
  for (int kt = 0; kt < 1024; kt += 128){
    __syncthreads();
    if (kt + 64 < 1024) stage(kt + 64, 1);
    compute(0, 0); compute(0, 1);
    __syncthreads();
    if (kt + 128 < 1024) stage(kt + 128, 0);
    compute(1, 0); compute(1, 1);
  }

  const bool isV = (n0 >= 2048);          // block-uniform
  #pragma unroll
  for (int i = 0; i < 4; i++){
    const int row0 = m0 + wr * 64 + i * 16 + q * 4;   // 4 consecutive tokens
    float atv[4];
    #pragma unroll
    for (int r = 0; r < 4; r++) atv[r] = at[row0 + r];
    float p[4] = {0.f, 0.f, 0.f, 0.f};
    #pragma unroll
    for (int j = 0; j < 4; j++){
      int col = n0 + wc * 64 + j * 16 + l15;
      float b0v = b0[col];
      float bv = (col < 1024) ? bias_a[col] : (col < 2048) ? bias_b[col - 1024] : bias_c[col - 2048];
      float vv[4];
      #pragma unroll
      for (int r = 0; r < 4; r++){
        vv[r] = acc[i][j][r] + atv[r] * b0v + bv;
        p[r] += vv[r] * vv[r];
      }
      if (!isV){
        #pragma unroll
        for (int r = 0; r < 4; r++)
          Cbf[(size_t)(row0 + r) * 3072 + col] = f2bf(vv[r]);
      } else {
        int vcol = col - 2048, hv = vcol >> 6, f = vcol & 63;
        int bb = row0 >> 10, sidx = row0 & 1023;
        union { uint2 u; u16 h[4]; } o;
        #pragma unroll
        for (int r = 0; r < 4; r++) o.h[r] = f2bf(vv[r]);
        *(uint2*)(vT + ((size_t)(bb * 16 + hv) * 65 + 1 + f) * 1024 + sidx) = o.u;
      }
    }
    #pragma unroll
    for (int r = 0; r < 4; r++){
      float s = p[r];
      s += __shfl_xor(s, 1, 64); s += __shfl_xor(s, 2, 64);
      s += __shfl_xor(s, 4, 64); s += __shfl_xor(s, 8, 64);
      if (l15 == 0){
        int row = row0 + r;
        int ch = (n0 + wc * 64) >> 6;       // head-chunk 0..47
        int bb = row >> 10, sidx = row & 1023;
        float t = sqrtf(s + 1.f);
        if (ch < 16)      qtv[((size_t)bb * 16 + ch) * 1024 + sidx] = t;
        else if (ch < 32) ktv[((size_t)bb * 16 + ch - 16) * 1024 + sidx] = t;
        else              vT[((size_t)(bb * 16 + ch - 32) * 65) * 1024 + sidx] = f2bf(t);
      }
    }
  }
}

// ---------------------------------------------------------------- generic GEMM 128x128 (modes 1/2)
__global__ __launch_bounds__(256) void gemm128(
    const u16* __restrict__ A, int lda, const u16* __restrict__ Bm, int ldb,
    const float* __restrict__ at, int at_mode, const float* __restrict__ b0,
    const float* __restrict__ bias_a,
    u16* __restrict__ Cbf, int ldc, int Kslice, int mode,
    float* __restrict__ rowsq)
{
  __shared__ u16 As[2][128 * 64];
  __shared__ u16 Bs[2][128 * 64];
  const int tid = threadIdx.x;
  const int w = tid >> 6, l = tid & 63;
  const int l15 = l & 15, q = l >> 4;
  const int m0 = blockIdx.y * 128, n0 = blockIdx.x * 128;
  const int ks = blockIdx.z;
  const int kbeg = ks * Kslice;
  const int kend = kbeg + Kslice;
  const int wr = w >> 1, wc = w & 1;
  f32x4 acc[4][4] = {};

  auto stage = [&](int kt, int buf){
    #pragma unroll
    for (int half = 0; half < 2; half++){
      #pragma unroll
      for (int i = 0; i < 2; i++){
        int s = (w * 2 + i) * 64 + l;
        int row = s >> 2;
        int kc = ((s & 3) - (s >> 3)) & 3;
        gl_lds16(A  + (size_t)(m0 + row) * lda + kt + half * 32 + kc * 8,
                 &As[buf][half * 4096 + (w * 2 + i) * 512]);
        gl_lds16(Bm + (size_t)(n0 + row) * ldb + kt + half * 32 + kc * 8,
                 &Bs[buf][half * 4096 + (w * 2 + i) * 512]);
      }
    }
  };
  auto compute = [&](int buf, int half){
    bf16x8 af[4], bfr[4];
    #pragma unroll
    for (int i = 0; i < 4; i++){
      int row = wr * 64 + i * 16 + l15;
      int slot = row * 4 + ((q + (row >> 1)) & 3);
      af[i] = *(const bf16x8*)&As[buf][half * 4096 + slot * 8];
    }
    #pragma unroll
    for (int j = 0; j < 4; j++){
      int row = wc * 64 + j * 16 + l15;
      int slot = row * 4 + ((q + (row >> 1)) & 3);
      bfr[j] = *(const bf16x8*)&Bs[buf][half * 4096 + slot * 8];
    }
    #pragma unroll
    for (int i = 0; i < 4; i++)
      #pragma unroll
      for (int j = 0; j < 4; j++)
        acc[i][j] = __builtin_amdgcn_mfma_f32_16x16x32_bf16(af[i], bfr[j], acc[i][j], 0, 0, 0);
  };

  stage(kbeg, 0);
  for (int kt = kbeg; kt < kend; kt += 128){
    __syncthreads();
    if (kt + 64 < kend) stage(kt + 64, 1);
    compute(0, 0); compute(0, 1);
    __syncthreads();
    if (kt + 128 < kend) stage(kt + 128, 0);
    compute(1, 0); compute(1, 1);
  }

  const size_t slice_off = (size_t)ks * (size_t)(gridDim.y * 128) * ldc;
  #pragma unroll
  for (int i = 0; i < 4; i++){
    float atv[4];
    #pragma unroll
    for (int r = 0; r < 4; r++){
      float a = at[m0 + wr * 64 + i * 16 + q * 4 + r];
      atv[r] = at_mode ? sqrtf(a + 1.f) : a;
    }
    float p[4] = {0.f, 0.f, 0.f, 0.f};
    #pragma unroll
    for (int j = 0; j < 4; j++){
      int col = n0 + wc * 64 + j * 16 + l15;
      float b0v = b0[col];
      float bv = bias_a[col];
      #pragma unroll
      for (int r = 0; r < 4; r++){
        size_t row = (size_t)(m0 + wr * 64 + i * 16 + q * 4 + r);
        float add = (ks == 0) ? (atv[r] * b0v + bv) : 0.f;
        float v = acc[i][j][r] + add;
        if (mode == 2) v = fmaxf(v, 0.f);
        Cbf[slice_off + row * ldc + col] = f2bf(v);
        if (mode == 2) p[r] += v * v;
      }
    }
    if (mode == 2){
      #pragma unroll
      for (int r = 0; r < 4; r++){
        float s = p[r];
        s += __shfl_xor(s, 1, 64); s += __shfl_xor(s, 2, 64);
        s += __shfl_xor(s, 4, 64); s += __shfl_xor(s, 8, 64);
        if (l15 == 0) atomicAdd(&rowsq[m0 + wr * 64 + i * 16 + q * 4 + r], s);
      }
    }
  }
}

// ---------------------------------------------------------------- flash attention
__global__ __launch_bounds__(512) void attn_kernel(
    const u16* __restrict__ qkv, const float* __restrict__ qt,
    const float* __restrict__ ktm, const u16* __restrict__ vT,
    u16* __restrict__ aout, float* __restrict__ aot_sq)
{
  __shared__ u16 smem[30720];   // 61440 B
  u16* Qlds = smem;                                   // [0,8192) prologue only
  u16* Kl0 = smem + 8192;                             // [8192,12288)
  u16* Kl1 = smem + 12288;                            // [12288,16384)
  u16* Vl0 = smem + 16384;                            // [16384,21504) 5120
  u16* Vl1 = smem;                                    // reuse Q region (5120)
  u16* Plds = smem + 21504;                           // [21504,30720) 9216
  const int tid = threadIdx.x;
  const int w = tid >> 6, l = tid & 63;
  const int l15 = l & 15, qd = l >> 4;
  const int q0 = blockIdx.x * 128;
  const int bh = blockIdx.y;
  const int b = bh >> 4, h = bh & 15;
  const size_t tokbase = (size_t)b << 10;

  #pragma unroll
  for (int i = 0; i < 2; i++){
    int c = i * 512 + w * 64 + l;                 // chunk slot 0..1023
    int row = c >> 3, kc = ((c & 7) - row) & 7;   // slot = row*8+((kc+row)&7)
    gl_lds16(qkv + (tokbase + q0 + row) * 3072 + h * 64 + kc * 8, &Qlds[(i * 512 + w * 64) * 8]);
  }
  __syncthreads();
  bf16x8 aq[2];
  {
    int row = w * 16 + l15;
    #pragma unroll
    for (int kk = 0; kk < 2; kk++)
      aq[kk] = *(const bf16x8*)&Qlds[(row * 8 + ((kk * 4 + qd + row) & 7)) * 8];
  }
  float tq[4];
  #pragma unroll
  for (int r = 0; r < 4; r++)
    tq[r] = qt[(size_t)bh * SEQ + q0 + w * 16 + qd * 4 + r];

  auto stage_kv = [&](int kt, int buf){
    u16* K = buf ? Kl1 : Kl0;
    u16* V = buf ? Vl1 : Vl0;
    int c = w * 64 + l;                           // 512 chunks
    int row = c >> 3, kc = ((c & 7) - row) & 7;
    gl_lds16(qkv + (tokbase + kt * 64 + row) * 3072 + 1024 + h * 64 + kc * 8, &K[w * 512]);
    gl_lds16(vT + ((size_t)bh * 65 + row) * 1024 + kt * 64 + kc * 8, &V[w * 512]);
    if (w == 0 && l < 8)                          // vT row 64: slots 512..519
      gl_lds16(vT + ((size_t)bh * 65 + 64) * 1024 + kt * 64 + (l & 7) * 8, &V[4096]);
  };

  float mrow[4] = {-1e30f, -1e30f, -1e30f, -1e30f};
  f32x4 acco[5] = {};

  stage_kv(0, 0);                                 // Q region untouched here
  for (int kt = 0; kt < 16; kt++){
    __syncthreads();    // buf(kt&1) K/V resident; (kt=0) all aq reads drained
    if (kt + 1 < 16) stage_kv(kt + 1, (kt + 1) & 1);
    u16* K = (kt & 1) ? Kl1 : Kl0;
    u16* V = (kt & 1) ? Vl1 : Vl0;

    float sc[4][4];
    float mx[4] = {-1e30f, -1e30f, -1e30f, -1e30f};
    #pragma unroll
    for (int ct = 0; ct < 4; ct++){
      f32x4 z = {0.f, 0.f, 0.f, 0.f};
      int key = ct * 16 + l15;
      __builtin_amdgcn_s_setprio(1);
      #pragma unroll
      for (int kk = 0; kk < 2; kk++){
        bf16x8 bk = *(const bf16x8*)&K[(key * 8 + ((kk * 4 + qd + key) & 7)) * 8];
        z = __builtin_amdgcn_mfma_f32_16x16x32_bf16(aq[kk], bk, z, 0, 0, 0);
      }
      __builtin_amdgcn_s_setprio(0);
      float tk = ktm[(size_t)bh * SEQ + kt * 64 + key];
      #pragma unroll
      for (int r = 0; r < 4; r++){
        float s = 0.25f + 0.25f * (z[r] - tq[r] * tk);
        sc[ct][r] = s;
        mx[r] = fmaxf(mx[r], s);
      }
    }
    #pragma unroll
    for (int r = 0; r < 4; r++){
      #pragma unroll
      for (int msk = 1; msk < 16; msk <<= 1)
        mx[r] = fmaxf(mx[r], __shfl_xor(mx[r], msk, 64));
      float mnew = fmaxf(mrow[r], mx[r]);
      float alpha = __expf(mrow[r] - mnew);
      mrow[r] = mnew;
      #pragma unroll
      for (int co = 0; co < 5; co++) acco[co][r] *= alpha;
      mx[r] = mnew;
    }
    #pragma unroll
    for (int ct = 0; ct < 4; ct++)
      #pragma unroll
      for (int r = 0; r < 4; r++)
        Plds[w * 1152 + (qd * 4 + r) * 72 + ct * 16 + l15] = f2bf(__expf(sc[ct][r] - mx[r]));
    asm volatile("s_waitcnt lgkmcnt(0)" ::: "memory");
    bf16x8 ap[2];
    #pragma unroll
    for (int kk = 0; kk < 2; kk++)
      ap[kk] = *(const bf16x8*)&Plds[w * 1152 + l15 * 72 + kk * 32 + qd * 8];
    __builtin_amdgcn_s_setprio(1);
    #pragma unroll
    for (int co = 0; co < 5; co++){
      int vtr = co * 16 + l15;
      #pragma unroll
      for (int kk = 0; kk < 2; kk++){
        bf16x8 bv = *(const bf16x8*)&V[(vtr * 8 + ((kk * 4 + qd + vtr) & 7)) * 8];
        acco[co] = __builtin_amdgcn_mfma_f32_16x16x32_bf16(ap[kk], bv, acco[co], 0, 0, 0);
      }
    }
    __builtin_amdgcn_s_setprio(0);
  }
  #pragma unroll
  for (int r = 0; r < 4; r++){
    float ss = 0.f;
    #pragma unroll
    for (int co = 0; co < 5; co++){
      int col = co * 16 + l15;
      float v = acco[co][r];
      if (col == 0) ss -= v * v;
      else if (col < 65) ss += v * v;
    }
    #pragma unroll
    for (int msk = 1; msk < 16; msk <<= 1) ss += __shfl_xor(ss, msk, 64);
    float v0b = __shfl(acco[0][r], l & 48, 64);       // time comp broadcast in 16-group
    float sp = ss + v0b * v0b;                        // sum of space^2
    float rn = rsqrtf(fmaxf(fabsf(ss), 1e-8f));
    size_t rowg = tokbase + q0 + w * 16 + qd * 4 + r;
    if (l15 == 0) atomicAdd(&aot_sq[rowg], sp * rn * rn);
    #pragma unroll
    for (int co = 0; co < 5; co++){
      int col = co * 16 + l15;
      if (col >= 1 && col < 65)
        aout[rowg * 1024 + h * 64 + col - 1] = f2bf(acco[co][r] * rn);
    }
  }
}

// ---------------------------------------------------------------- midpoint + hyp_layernorm
__device__ __forceinline__ void block_sum3(float& a, float& b, float& c, float* red){
  int tid = threadIdx.x;
  #pragma unroll
  for (int m = 1; m < 64; m <<= 1){
    a += __shfl_xor(a, m, 64);
    b += __shfl_xor(b, m, 64);
    c += __shfl_xor(c, m, 64);
  }
  __syncthreads();
  if ((tid & 63) == 0){ int w = tid >> 6; red[w] = a; red[4 + w] = b; red[8 + w] = c; }
  __syncthreads();
  a = red[0] + red[1] + red[2] + red[3];
  b = red[4] + red[5] + red[6] + red[7];
  c = red[8] + red[9] + red[10] + red[11];
}
__device__ __forceinline__ float block_sum(float v, float* red){
  int tid = threadIdx.x;
  #pragma unroll
  for (int m = 1; m < 64; m <<= 1) v += __shfl_xor(v, m, 64);
  __syncthreads();
  if ((tid & 63) == 0) red[tid >> 6] = v;
  __syncthreads();
  return red[0] + red[1] + red[2] + red[3];
}

__global__ __launch_bounds__(256) void mid_ln(
    const u16* __restrict__ z, const u16* __restrict__ xsb, const float* __restrict__ xtv,
    const float* __restrict__ gam, const float* __restrict__ bet,
    u16* __restrict__ ob, float* __restrict__ ot,
    float* __restrict__ ofull, int mode_out, int nsl)
{
  __shared__ float red[12];
  const int tid = threadIdx.x;
  const int tok = blockIdx.x;
  const int i0 = tid * 4;
  float zv[4], xv[4], av[4];
  float xtime = xtv[tok];
  {
    union { uint2 u; u16 h[4]; } xu;
    xu.u = *(const uint2*)(xsb + (size_t)tok * 1024 + i0);
    #pragma unroll
    for (int j = 0; j < 4; j++) xv[j] = bf2f(xu.h[j]);
  }
  #pragma unroll
  for (int j = 0; j < 4; j++) zv[j] = 0.f;
  for (int s = 0; s < nsl; s++){
    union { uint2 u; u16 h[4]; } zu;
    zu.u = *(const uint2*)(z + (size_t)s * NTOK * 1024 + (size_t)tok * 1024 + i0);
    #pragma unroll
    for (int j = 0; j < 4; j++) zv[j] += bf2f(zu.h[j]);
  }
  float ssz = 0.f, ssa = 0.f, sa = 0.f;
  #pragma unroll
  for (int j = 0; j < 4; j++){
    ssz += zv[j] * zv[j];
    av[j] = 0.5f * (zv[j] + xv[j]);
    ssa += av[j] * av[j];
    sa += av[j];
  }
  block_sum3(ssz, ssa, sa, red);
  float tz = sqrtf(ssz + 1.f);
  float avt = 0.5f * (tz + xtime);
  float rn = rsqrtf(fmaxf(fabsf(ssa - avt * avt), 1e-8f));
  float mu = sa * rn * (1.f / 1024.f);
  float squ = ssa * rn * rn;
  float var = squ * (1.f / 1024.f) - mu * mu;
  float rv = rsqrtf(fmaxf(var, 0.f) + 1e-5f);
  float g4[4], b4[4];
  *(float4*)g4 = *(const float4*)(gam + i0);
  *(float4*)b4 = *(const float4*)(bet + i0);
  float sv[4]; float sss = 0.f;
  #pragma unroll
  for (int j = 0; j < 4; j++){
    sv[j] = (av[j] * rn - mu) * rv * g4[j] + b4[j];
    sss += sv[j] * sv[j];
  }
  sss = block_sum(sss, red);
  float tout = sqrtf(sss + 1.f);
  if (mode_out == 0){
    union { uint2 u; u16 h[4]; } o;
    #pragma unroll
    for (int j = 0; j < 4; j++) o.h[j] = f2bf(sv[j]);
    *(uint2*)(ob + (size_t)tok * 1024 + i0) = o.u;
    if (tid == 0) ot[tok] = tout;
  } else {
    float* orow = ofull + (size_t)tok * 1025;
    #pragma unroll
    for (int j = 0; j < 4; j++) orow[1 + i0 + j] = sv[j];
    if (tid == 0) orow[0] = tout;
  }
}

// ---------------------------------------------------------------- launch
extern "C" void kernel_launch(void* const* d_in, const int* in_sizes, int n_in,
                              void* d_out, int out_size, void* d_ws, size_t ws_size,
                              hipStream_t stream){
  const float* x   = (const float*)d_in[0];
  const float* Wq  = (const float*)d_in[1];
  const float* bq  = (const float*)d_in[2];
  const float* Wk  = (const float*)d_in[3];
  const float* bk  = (const float*)d_in[4];
  const float* Wv  = (const float*)d_in[5];
  const float* bv  = (const float*)d_in[6];
  const float* Wo  = (const float*)d_in[7];
  const float* bo  = (const float*)d_in[8];
  const float* g1  = (const float*)d_in[9];
  const float* be1 = (const float*)d_in[10];
  const float* W1  = (const float*)d_in[11];
  const float* c1  = (const float*)d_in[12];
  const float* W2  = (const float*)d_in[13];
  const float* c2  = (const float*)d_in[14];
  const float* g2  = (const float*)d_in[15];
  const float* be2 = (const float*)d_in[16];
  float* out = (float*)d_out;

  char* p = (char*)d_ws;
  auto take = [&](size_t n){ char* r = p; p += (n + 255) & ~(size_t)255; return r; };
  u16*   xs    = (u16*)  take((size_t)NTOK * 1024 * 2);
  float* xt    = (float*)take(NTOK * 4);
  u16*   wqkv  = (u16*)  take((size_t)3072 * 1024 * 2);
  float* wqkv0 = (float*)take(3072 * 4);
  u16*   wo_s  = (u16*)  take((size_t)1024 * 1024 * 2);
  float* wo0   = (float*)take(1024 * 4);
  u16*   w1_s  = (u16*)  take((size_t)4096 * 1024 * 2);
  float* w10   = (float*)take(4096 * 4);
  u16*   w2_s  = (u16*)  take((size_t)1024 * 4096 * 2);
  float* w20   = (float*)take(1024 * 4);
  u16*   qkvb  = (u16*)  take((size_t)NTOK * 3072 * 2);
  float* qtv   = (float*)take((size_t)64 * 1024 * 4);
  float* ktv   = (float*)take((size_t)64 * 1024 * 4);
  u16*   vT    = (u16*)  take((size_t)64 * 65 * 1024 * 2);
  u16*   aoutb = (u16*)  take((size_t)NTOK * 1024 * 2);
  float* sqbuf = (float*)take((size_t)2 * NTOK * 4);   // aot_sq | htv_sq (zeroed in conv_all)
  float* aot_sq = sqbuf;
  float* htv_sq = sqbuf + NTOK;
  u16*   zbuf  = (u16*)  take((size_t)4 * NTOK * 1024 * 2);   // up to 4 split-K bf16 slices
  u16*   x1b   = (u16*)  take((size_t)NTOK * 1024 * 2);
  float* x1t   = (float*)take(NTOK * 4);
  u16*   hbuf  = (u16*)  take((size_t)NTOK * 4096 * 2);

  // fused prologue: conv_x + conv_w_all + sqbuf zero (one launch)
  conv_all<<<4100 + 12297 + 32, 256, 0, stream>>>(
      x, Wq, Wk, Wv, Wo, W1, W2,
      xs, xt, wqkv, wo_s, w1_s, w2_s, wqkv0, wo0, w10, w20, sqbuf);

  // QKV + fused time norms + direct transposed V write (v_transpose eliminated)
  gemm128_qkv<<<dim3(24, 32), 256, 0, stream>>>(xs, wqkv, xt, wqkv0,
      bq, bk, bv, qkvb, qtv, ktv, vT);
  attn_kernel<<<dim3(8, 64), 512, 0, stream>>>(qkvb, qtv, ktv, vT, aoutb, aot_sq);
  // O-proj: split-K x2 (512 blocks), bf16 partial slices
  gemm128<<<dim3(8, 32, 2), 256, 0, stream>>>(aoutb, 1024, wo_s, 1024, aot_sq, 1, wo0,
      bo, zbuf, 1024, 512, 1, nullptr);
  mid_ln<<<NTOK, 256, 0, stream>>>(zbuf, xs, xt, g1, be1,
      x1b, x1t, nullptr, 0, 2);
  // MLP1 + relu + fused row sum-of-squares (M=4096, N=4096, K=1024) — 1024 blocks
  gemm128<<<dim3(32, 32), 256, 0, stream>>>(x1b, 1024, w1_s, 1024, x1t, 0, w10,
      c1, hbuf, 4096, 1024, 2, htv_sq);
  // MLP2: split-K x2 (512 blocks), Kslice 2048
  gemm128<<<dim3(8, 32, 2), 256, 0, stream>>>(hbuf, 4096, w2_s, 4096, htv_sq, 1, w20,
      c2, zbuf, 1024, 2048, 1, nullptr);
  mid_ln<<<NTOK, 256, 0, stream>>>(zbuf, x1b, x1t, g2, be2,
      nullptr, nullptr, out, 1, 2);
}

// Round 13
// 376.732 us; speedup vs baseline: 1.0253x; 1.0253x over previous
//
#include <hip/hip_runtime.h>

typedef unsigned short u16;
typedef unsigned int   u32;
typedef short bf16x8 __attribute__((ext_vector_type(8)));
typedef float f32x4  __attribute__((ext_vector_type(4)));

#define NTOK 4096   // B*S
#define SEQ  1024

__device__ __forceinline__ u16 f2bf(float f){
  union { float f; u32 u; } x; x.f = f;
  u32 r = (x.u + 0x7FFFu + ((x.u >> 16) & 1u)) >> 16;
  return (u16)r;
}
__device__ __forceinline__ float bf2f(u16 u){
  union { u32 u; float f; } x; x.u = ((u32)u) << 16; return x.f;
}
__device__ __forceinline__ void gl_lds16(const void* gp, void* lp){
  __builtin_amdgcn_global_load_lds(
      (const __attribute__((address_space(1))) u32*)gp,
      (__attribute__((address_space(3))) u32*)lp, 16, 0, 0);
}

// ---------------------------------------------------------------- fused prologue
// One launch: conv_x + conv_w_all + sqbuf zero. Region boundaries block-aligned.
__global__ __launch_bounds__(256) void conv_all(
    const float* __restrict__ x,
    const float* __restrict__ Wq, const float* __restrict__ Wk,
    const float* __restrict__ Wv, const float* __restrict__ Wo,
    const float* __restrict__ W1, const float* __restrict__ W2,
    u16* __restrict__ xs, float* __restrict__ xt,
    u16* __restrict__ wqkv, u16* __restrict__ wo_s, u16* __restrict__ w1_s, u16* __restrict__ w2_s,
    float* __restrict__ wqkv0, float* __restrict__ wo0, float* __restrict__ w10, float* __restrict__ w20,
    float* __restrict__ sqbuf)
{
  int t = blockIdx.x * 256 + threadIdx.x;
  const int QX = 1049600;                 // x quads (4100 blocks)
  const int Q1 = 262400;                  // quads per 1024x1025 weight
  const int QW = 4 * Q1 + 1049600 + 1048832;   // 3,148,032 (12297 blocks)
  if (t < QX){
    int e = t * 4;
    int r = (u32)e / 1025u;
    int c = e - r * 1025;
    float4 v = *(const float4*)(x + (size_t)e);
    const float* vp = (const float*)&v;
    #pragma unroll
    for (int k = 0; k < 4; k++){
      if (c == 0) xt[r] = vp[k];
      else xs[(size_t)r * 1024 + (c - 1)] = f2bf(vp[k]);
      if (++c == 1025){ c = 0; ++r; }
    }
    return;
  }
  t -= QX;
  if (t < QW){
    const float* W; u16* Wb; float* w0; int divr, Kin, e;
    if (t < 4 * Q1){
      int region = t / Q1; int qq = t - region * Q1;
      e = qq * 4; divr = 1025; Kin = 1024;
      if (region == 0)      { W = Wq; Wb = wqkv;             w0 = wqkv0; }
      else if (region == 1) { W = Wk; Wb = wqkv + (1 << 20); w0 = wqkv0 + 1024; }
      else if (region == 2) { W = Wv; Wb = wqkv + (2 << 20); w0 = wqkv0 + 2048; }
      else                  { W = Wo; Wb = wo_s;             w0 = wo0; }
    } else if (t < 4 * Q1 + 1049600){
      e = (t - 4 * Q1) * 4; divr = 1025; Kin = 1024; W = W1; Wb = w1_s; w0 = w10;
    } else {
      e = (t - 4 * Q1 - 1049600) * 4; divr = 4097; Kin = 4096; W = W2; Wb = w2_s; w0 = w20;
    }
    int r = (divr == 1025) ? (int)((u32)e / 1025u) : (int)((u32)e / 4097u);
    int c = e - r * divr;
    float4 v = *(const float4*)(W + (size_t)e);
    const float* vp = (const float*)&v;
    #pragma unroll
    for (int k = 0; k < 4; k++){
      if (c == 0) w0[r] = vp[k];
      else Wb[(size_t)r * Kin + (c - 1)] = f2bf(vp[k]);
      if (++c == divr){ c = 0; ++r; }
    }
    return;
  }
  t -= QW;
  if (t < 2 * NTOK) sqbuf[t] = 0.f;       // aot_sq | htv_sq zero (32 blocks)
}

// ---------------------------------------------------------------- QKV GEMM (isolated, mode-0; V written transposed)
// Q/K blocks (n0 < 2048): qkvb + qtv/ktv time rows as before.
// V blocks (n0 >= 2048, block-uniform): transpose through the dead As/Bs
// staging LDS (two [64][136] feature-major tiles; 136-u16 stride keeps rows
// 16B-aligned, <=4-way write / 2-way read bank aliasing), then stream 2048
// fully-coalesced 16B chunks to vT (each 16-lane group writes 256 contiguous
// bytes of one feature row). Round-12's direct 8B scatter cost ~10us on this
// dispatch (MfmaUtil 15.3 vs 21.4 on siblings).
__global__ __launch_bounds__(256) void gemm128_qkv(
    const u16* __restrict__ A, const u16* __restrict__ Bm,
    const float* __restrict__ at, const float* __restrict__ b0,
    const float* __restrict__ bias_a, const float* __restrict__ bias_b, const float* __restrict__ bias_c,
    u16* __restrict__ Cbf,
    float* __restrict__ qtv, float* __restrict__ ktv, u16* __restrict__ vT)
{
  __shared__ u16 As[2][128 * 64];
  __shared__ u16 Bs[2][128 * 64];
  const int tid = threadIdx.x;
  const int w = tid >> 6, l = tid & 63;
  const int l15 = l & 15, q = l >> 4;
  const int m0 = blockIdx.y * 128, n0 = blockIdx.x * 128;
  const int wr = w >> 1, wc = w & 1;
  f32x4 acc[4][4] = {};

  auto stage = [&](int kt, int buf){
    #pragma unroll
    for (int half = 0; half < 2; half++){
      #pragma unroll
      for (int i = 0; i < 2; i++){
        int s = (w * 2 + i) * 64 + l;
        int row = s >> 2;
        int kc = ((s & 3) - (s >> 3)) & 3;
        gl_lds16(A  + (size_t)(m0 + row) * 1024 + kt + half * 32 + kc * 8,
                 &As[buf][half * 4096 + (w * 2 + i) * 512]);
        gl_lds16(Bm + (size_t)(n0 + row) * 1024 + kt + half * 32 + kc * 8,
                 &Bs[buf][half * 4096 + (w * 2 + i) * 512]);
      }
    }
  };
  auto compute = [&](int buf, int half){
    bf16x8 af[4], bfr[4];
    #pragma unroll
    for (int i = 0; i < 4; i++){
      int row = wr * 64 + i * 16 + l15;
      int slot = row * 4 + ((q + (row >> 1)) & 3);
      af[i] = *(const bf16x8*)&As[buf][half * 4096 + slot * 8];
    }
    #pragma unroll
    for (int j = 0; j < 4; j++){
      int row = wc * 64 + j * 16 + l15;
      int slot = row * 4 + ((q + (row >> 1)) & 3);
      bfr[j] = *(const bf16x8*)&Bs[buf][half * 4096 + slot * 8];
    }
    #pragma unroll
    for (int i = 0; i < 4; i++)
      #pragma unroll
      for (int j = 0; j < 4; j++)
        acc[i][j] = __builtin_amdgcn_mfma_f32_16x16x32_bf16(af[i], bfr[j], acc[i][j], 0, 0, 0);
  };

  stage(0, 0);
  for (int kt = 0; kt < 1024; kt += 128){
    __syncthreads();
    if (kt + 64 < 1024) stage(kt + 64, 1);
    compute(0, 0); compute(0, 1);
    __syncthreads();
    if (kt + 128 < 1024) stage(kt + 128, 0);
    compute(1, 0); compute(1, 1);
  }

  const bool isV = (n0 >= 2048);          // block-uniform
  if (!isV){
    #pragma unroll
    for (int i = 0; i < 4; i++){
      const int row0 = m0 + wr * 64 + i * 16 + q * 4;   // 4 consecutive tokens
      float atv[4];
      #pragma unroll
      for (int r = 0; r < 4; r++) atv[r] = at[row0 + r];
      float p[4] = {0.f, 0.f, 0.f, 0.f};
      #pragma unroll
      for (int j = 0; j < 4; j++){
        int col = n0 + wc * 64 + j * 16 + l15;
        float b0v = b0[col];
        float bv = (col < 1024) ? bias_a[col] : bias_b[col - 1024];
        #pragma unroll
        for (int r = 0; r < 4; r++){
          float vv = acc[i][j][r] + atv[r] * b0v + bv;
          p[r] += vv * vv;
          Cbf[(size_t)(row0 + r) * 3072 + col] = f2bf(vv);
        }
      }
      #pragma unroll
      for (int r = 0; r < 4; r++){
        float s = p[r];
        s += __shfl_xor(s, 1, 64); s += __shfl_xor(s, 2, 64);
        s += __shfl_xor(s, 4, 64); s += __shfl_xor(s, 8, 64);
        if (l15 == 0){
          int row = row0 + r;
          int ch = (n0 + wc * 64) >> 6;       // 0..31
          int bb = row >> 10, sidx = row & 1023;
          float t = sqrtf(s + 1.f);
          if (ch < 16) qtv[((size_t)bb * 16 + ch) * 1024 + sidx] = t;
          else         ktv[((size_t)bb * 16 + ch - 16) * 1024 + sidx] = t;
        }
      }
    }
  } else {
    // ---- V: transpose through LDS scratch, then coalesced 16B writes
    u16* scr0 = (u16*)As;                 // features 0..63   [64][136]
    u16* scr1 = (u16*)Bs;                 // features 64..127 [64][136]
    __syncthreads();                      // all K-loop LDS reads done
    #pragma unroll
    for (int i = 0; i < 4; i++){
      const int tloc0 = wr * 64 + i * 16 + q * 4;       // 4 consecutive local tokens
      const int row0 = m0 + tloc0;
      float atv[4];
      #pragma unroll
      for (int r = 0; r < 4; r++) atv[r] = at[row0 + r];
      float p[4] = {0.f, 0.f, 0.f, 0.f};
      u16* scr = wc ? scr1 : scr0;
      #pragma unroll
      for (int j = 0; j < 4; j++){
        int col = n0 + wc * 64 + j * 16 + l15;
        float b0v = b0[col];
        float bv = bias_c[col - 2048];
        union { uint2 u; u16 h[4]; } o;
        #pragma unroll
        for (int r = 0; r < 4; r++){
          float vv = acc[i][j][r] + atv[r] * b0v + bv;
          p[r] += vv * vv;
          o.h[r] = f2bf(vv);
        }
        *(uint2*)&scr[(j * 16 + l15) * 136 + tloc0] = o.u;
      }
      #pragma unroll
      for (int r = 0; r < 4; r++){
        float s = p[r];
        s += __shfl_xor(s, 1, 64); s += __shfl_xor(s, 2, 64);
        s += __shfl_xor(s, 4, 64); s += __shfl_xor(s, 8, 64);
        if (l15 == 0){
          int row = row0 + r;
          int ch = (n0 + wc * 64) >> 6;       // 32..47
          int bb = row >> 10, sidx = row & 1023;
          vT[((size_t)(bb * 16 + ch - 32) * 65) * 1024 + sidx] = f2bf(sqrtf(s + 1.f));
        }
      }
    }
    __syncthreads();                      // scratch complete
    const int hvbase = (n0 - 2048) >> 6;
    const int bb = m0 >> 10, sbase = m0 & 1023;
    for (int c = tid; c < 2048; c += 256){
      int f = c >> 4, tc = c & 15;        // feature 0..127, token-chunk 0..15
      const u16* scr = (f < 64) ? scr0 : scr1;
      uint4 d = *(const uint4*)&scr[(f & 63) * 136 + tc * 8];
      int hv = hvbase + (f >> 6), fl = f & 63;
      *(uint4*)(vT + ((size_t)(bb * 16 + hv) * 65 + 1 + fl) * 1024 + sbase + tc * 8) = d;
    }
  }
}

// ---------------------------------------------------------------- generic GEMM 128x128 (modes 1/2)
__global__ __launch_bounds__(256) void gemm128(
    const u16* __restrict__ A, int lda, const u16* __restrict__ Bm, int ldb,
    const float* __restrict__ at, int at_mode, const float* __restrict__ b0,
    const float* __restrict__ bias_a,
    u16* __restrict__ Cbf, int ldc, int Kslice, int mode,
    float* __restrict__ rowsq)
{
  __shared__ u16 As[2][128 * 64];
  __shared__ u16 Bs[2][128 * 64];
  const int tid = threadIdx.x;
  const int w = tid >> 6, l = tid & 63;
  const int l15 = l & 15, q = l >> 4;
  const int m0 = blockIdx.y * 128, n0 = blockIdx.x * 128;
  const int ks = blockIdx.z;
  const int kbeg = ks * Kslice;
  const int kend = kbeg + Kslice;
  const int wr = w >> 1, wc = w & 1;
  f32x4 acc[4][4] = {};

  auto stage = [&](int kt, int buf){
    #pragma unroll
    for (int half = 0; half < 2; half++){
      #pragma unroll
      for (int i = 0; i < 2; i++){
        int s = (w * 2 + i) * 64 + l;
        int row = s >> 2;
        int kc = ((s & 3) - (s >> 3)) & 3;
        gl_lds16(A  + (size_t)(m0 + row) * lda + kt + half * 32 + kc * 8,
                 &As[buf][half * 4096 + (w * 2 + i) * 512]);
        gl_lds16(Bm + (size_t)(n0 + row) * ldb + kt + half * 32 + kc * 8,
                 &Bs[buf][half * 4096 + (w * 2 + i) * 512]);
      }
    }
  };
  auto compute = [&](int buf, int half){
    bf16x8 af[4], bfr[4];
    #pragma unroll
    for (int i = 0; i < 4; i++){
      int row = wr * 64 + i * 16 + l15;
      int slot = row * 4 + ((q + (row >> 1)) & 3);
      af[i] = *(const bf16x8*)&As[buf][half * 4096 + slot * 8];
    }
    #pragma unroll
    for (int j = 0; j < 4; j++){
      int row = wc * 64 + j * 16 + l15;
      int slot = row * 4 + ((q + (row >> 1)) & 3);
      bfr[j] = *(const bf16x8*)&Bs[buf][half * 4096 + slot * 8];
    }
    #pragma unroll
    for (int i = 0; i < 4; i++)
      #pragma unroll
      for (int j = 0; j < 4; j++)
        acc[i][j] = __builtin_amdgcn_mfma_f32_16x16x32_bf16(af[i], bfr[j], acc[i][j], 0, 0, 0);
  };

  stage(kbeg, 0);
  for (int kt = kbeg; kt < kend; kt += 128){
    __syncthreads();
    if (kt + 64 < kend) stage(kt + 64, 1);
    compute(0, 0); compute(0, 1);
    __syncthreads();
    if (kt + 128 < kend) stage(kt + 128, 0);
    compute(1, 0); compute(1, 1);
  }

  const size_t slice_off = (size_t)ks * (size_t)(gridDim.y * 128) * ldc;
  #pragma unroll
  for (int i = 0; i < 4; i++){
    float atv[4];
    #pragma unroll
    for (int r = 0; r < 4; r++){
      float a = at[m0 + wr * 64 + i * 16 + q * 4 + r];
      atv[r] = at_mode ? sqrtf(a + 1.f) : a;
    }
    float p[4] = {0.f, 0.f, 0.f, 0.f};
    #pragma unroll
    for (int j = 0; j < 4; j++){
      int col = n0 + wc * 64 + j * 16 + l15;
      float b0v = b0[col];
      float bv = bias_a[col];
      #pragma unroll
      for (int r = 0; r < 4; r++){
        size_t row = (size_t)(m0 + wr * 64 + i * 16 + q * 4 + r);
        float add = (ks == 0) ? (atv[r] * b0v + bv) : 0.f;
        float v = acc[i][j][r] + add;
        if (mode == 2) v = fmaxf(v, 0.f);
        Cbf[slice_off + row * ldc + col] = f2bf(v);
        if (mode == 2) p[r] += v * v;
      }
    }
    if (mode == 2){
      #pragma unroll
      for (int r = 0; r < 4; r++){
        float s = p[r];
        s += __shfl_xor(s, 1, 64); s += __shfl_xor(s, 2, 64);
        s += __shfl_xor(s, 4, 64); s += __shfl_xor(s, 8, 64);
        if (l15 == 0) atomicAdd(&rowsq[m0 + wr * 64 + i * 16 + q * 4 + r], s);
      }
    }
  }
}

// ---------------------------------------------------------------- flash attention
__global__ __launch_bounds__(512) void attn_kernel(
    const u16* __restrict__ qkv, const float* __restrict__ qt,
    const float* __restrict__ ktm, const u16* __restrict__ vT,
    u16* __restrict__ aout, float* __restrict__ aot_sq)
{
  __shared__ u16 smem[30720];   // 61440 B
  u16* Qlds = smem;                                   // [0,8192) prologue only
  u16* Kl0 = smem + 8192;                             // [8192,12288)
  u16* Kl1 = smem + 12288;                            // [12288,16384)
  u16* Vl0 = smem + 16384;                            // [16384,21504) 5120
  u16* Vl1 = smem;                                    // reuse Q region (5120)
  u16* Plds = smem + 21504;                           // [21504,30720) 9216
  const int tid = threadIdx.x;
  const int w = tid >> 6, l = tid & 63;
  const int l15 = l & 15, qd = l >> 4;
  const int q0 = blockIdx.x * 128;
  const int bh = blockIdx.y;
  const int b = bh >> 4, h = bh & 15;
  const size_t tokbase = (size_t)b << 10;

  #pragma unroll
  for (int i = 0; i < 2; i++){
    int c = i * 512 + w * 64 + l;                 // chunk slot 0..1023
    int row = c >> 3, kc = ((c & 7) - row) & 7;   // slot = row*8+((kc+row)&7)
    gl_lds16(qkv + (tokbase + q0 + row) * 3072 + h * 64 + kc * 8, &Qlds[(i * 512 + w * 64) * 8]);
  }
  __syncthreads();
  bf16x8 aq[2];
  {
    int row = w * 16 + l15;
    #pragma unroll
    for (int kk = 0; kk < 2; kk++)
      aq[kk] = *(const bf16x8*)&Qlds[(row * 8 + ((kk * 4 + qd + row) & 7)) * 8];
  }
  float tq[4];
  #pragma unroll
  for (int r = 0; r < 4; r++)
    tq[r] = qt[(size_t)bh * SEQ + q0 + w * 16 + qd * 4 + r];

  auto stage_kv = [&](int kt, int buf){
    u16* K = buf ? Kl1 : Kl0;
    u16* V = buf ? Vl1 : Vl0;
    int c = w * 64 + l;                           // 512 chunks
    int row = c >> 3, kc = ((c & 7) - row) & 7;
    gl_lds16(qkv + (tokbase + kt * 64 + row) * 3072 + 1024 + h * 64 + kc * 8, &K[w * 512]);
    gl_lds16(vT + ((size_t)bh * 65 + row) * 1024 + kt * 64 + kc * 8, &V[w * 512]);
    if (w == 0 && l < 8)                          // vT row 64: slots 512..519
      gl_lds16(vT + ((size_t)bh * 65 + 64) * 1024 + kt * 64 + (l & 7) * 8, &V[4096]);
  };

  float mrow[4] = {-1e30f, -1e30f, -1e30f, -1e30f};
  f32x4 acco[5] = {};

  stage_kv(0, 0);                                 // Q region untouched here
  for (int kt = 0; kt < 16; kt++){
    __syncthreads();    // buf(kt&1) K/V resident; (kt=0) all aq reads drained
    if (kt + 1 < 16) stage_kv(kt + 1, (kt + 1) & 1);
    u16* K = (kt & 1) ? Kl1 : Kl0;
    u16* V = (kt & 1) ? Vl1 : Vl0;

    float sc[4][4];
    float mx[4] = {-1e30f, -1e30f, -1e30f, -1e30f};
    #pragma unroll
    for (int ct = 0; ct < 4; ct++){
      f32x4 z = {0.f, 0.f, 0.f, 0.f};
      int key = ct * 16 + l15;
      __builtin_amdgcn_s_setprio(1);
      #pragma unroll
      for (int kk = 0; kk < 2; kk++){
        bf16x8 bk = *(const bf16x8*)&K[(key * 8 + ((kk * 4 + qd + key) & 7)) * 8];
        z = __builtin_amdgcn_mfma_f32_16x16x32_bf16(aq[kk], bk, z, 0, 0, 0);
      }
      __builtin_amdgcn_s_setprio(0);
      float tk = ktm[(size_t)bh * SEQ + kt * 64 + key];
      #pragma unroll
      for (int r = 0; r < 4; r++){
        float s = 0.25f + 0.25f * (z[r] - tq[r] * tk);
        sc[ct][r] = s;
        mx[r] = fmaxf(mx[r], s);
      }
    }
    #pragma unroll
    for (int r = 0; r < 4; r++){
      #pragma unroll
      for (int msk = 1; msk < 16; msk <<= 1)
        mx[r] = fmaxf(mx[r], __shfl_xor(mx[r], msk, 64));
      float mnew = fmaxf(mrow[r], mx[r]);
      float alpha = __expf(mrow[r] - mnew);
      mrow[r] = mnew;
      #pragma unroll
      for (int co = 0; co < 5; co++) acco[co][r] *= alpha;
      mx[r] = mnew;
    }
    #pragma unroll
    for (int ct = 0; ct < 4; ct++)
      #pragma unroll
      for (int r = 0; r < 4; r++)
        Plds[w * 1152 + (qd * 4 + r) * 72 + ct * 16 + l15] = f2bf(__expf(sc[ct][r] - mx[r]));
    asm volatile("s_waitcnt lgkmcnt(0)" ::: "memory");
    bf16x8 ap[2];
    #pragma unroll
    for (int kk = 0; kk < 2; kk++)
      ap[kk] = *(const bf16x8*)&Plds[w * 1152 + l15 * 72 + kk * 32 + qd * 8];
    __builtin_amdgcn_s_setprio(1);
    #pragma unroll
    for (int co = 0; co < 5; co++){
      int vtr = co * 16 + l15;
      #pragma unroll
      for (int kk = 0; kk < 2; kk++){
        bf16x8 bv = *(const bf16x8*)&V[(vtr * 8 + ((kk * 4 + qd + vtr) & 7)) * 8];
        acco[co] = __builtin_amdgcn_mfma_f32_16x16x32_bf16(ap[kk], bv, acco[co], 0, 0, 0);
      }
    }
    __builtin_amdgcn_s_setprio(0);
  }
  #pragma unroll
  for (int r = 0; r < 4; r++){
    float ss = 0.f;
    #pragma unroll
    for (int co = 0; co < 5; co++){
      int col = co * 16 + l15;
      float v = acco[co][r];
      if (col == 0) ss -= v * v;
      else if (col < 65) ss += v * v;
    }
    #pragma unroll
    for (int msk = 1; msk < 16; msk <<= 1) ss += __shfl_xor(ss, msk, 64);
    float v0b = __shfl(acco[0][r], l & 48, 64);       // time comp broadcast in 16-group
    float sp = ss + v0b * v0b;                        // sum of space^2
    float rn = rsqrtf(fmaxf(fabsf(ss), 1e-8f));
    size_t rowg = tokbase + q0 + w * 16 + qd * 4 + r;
    if (l15 == 0) atomicAdd(&aot_sq[rowg], sp * rn * rn);
    #pragma unroll
    for (int co = 0; co < 5; co++){
      int col = co * 16 + l15;
      if (col >= 1 && col < 65)
        aout[rowg * 1024 + h * 64 + col - 1] = f2bf(acco[co][r] * rn);
    }
  }
}

// ---------------------------------------------------------------- midpoint + hyp_layernorm
__device__ __forceinline__ void block_sum3(float& a, float& b, float& c, float* red){
  int tid = threadIdx.x;
  #pragma unroll
  for (int m = 1; m < 64; m <<= 1){
    a += __shfl_xor(a, m, 64);
    b += __shfl_xor(b, m, 64);
    c += __shfl_xor(c, m, 64);
  }
  __syncthreads();
  if ((tid & 63) == 0){ int w = tid >> 6; red[w] = a; red[4 + w] = b; red[8 + w] = c; }
  __syncthreads();
  a = red[0] + red[1] + red[2] + red[3];
  b = red[4] + red[5] + red[6] + red[7];
  c = red[8] + red[9] + red[10] + red[11];
}
__device__ __forceinline__ float block_sum(float v, float* red){
  int tid = threadIdx.x;
  #pragma unroll
  for (int m = 1; m < 64; m <<= 1) v += __shfl_xor(v, m, 64);
  __syncthreads();
  if ((tid & 63) == 0) red[tid >> 6] = v;
  __syncthreads();
  return red[0] + red[1] + red[2] + red[3];
}

__global__ __launch_bounds__(256) void mid_ln(
    const u16* __restrict__ z, const u16* __restrict__ xsb, const float* __restrict__ xtv,
    const float* __restrict__ gam, const float* __restrict__ bet,
    u16* __restrict__ ob, float* __restrict__ ot,
    float* __restrict__ ofull, int mode_out, int nsl)
{
  __shared__ float red[12];
  const int tid = threadIdx.x;
  const int tok = blockIdx.x;
  const int i0 = tid * 4;
  float zv[4], xv[4], av[4];
  float xtime = xtv[tok];
  {
    union { uint2 u; u16 h[4]; } xu;
    xu.u = *(const uint2*)(xsb + (size_t)tok * 1024 + i0);
    #pragma unroll
    for (int j = 0; j < 4; j++) xv[j] = bf2f(xu.h[j]);
  }
  #pragma unroll
  for (int j = 0; j < 4; j++) zv[j] = 0.f;
  for (int s = 0; s < nsl; s++){
    union { uint2 u; u16 h[4]; } zu;
    zu.u = *(const uint2*)(z + (size_t)s * NTOK * 1024 + (size_t)tok * 1024 + i0);
    #pragma unroll
    for (int j = 0; j < 4; j++) zv[j] += bf2f(zu.h[j]);
  }
  float ssz = 0.f, ssa = 0.f, sa = 0.f;
  #pragma unroll
  for (int j = 0; j < 4; j++){
    ssz += zv[j] * zv[j];
    av[j] = 0.5f * (zv[j] + xv[j]);
    ssa += av[j] * av[j];
    sa += av[j];
  }
  block_sum3(ssz, ssa, sa, red);
  float tz = sqrtf(ssz + 1.f);
  float avt = 0.5f * (tz + xtime);
  float rn = rsqrtf(fmaxf(fabsf(ssa - avt * avt), 1e-8f));
  float mu = sa * rn * (1.f / 1024.f);
  float squ = ssa * rn * rn;
  float var = squ * (1.f / 1024.f) - mu * mu;
  float rv = rsqrtf(fmaxf(var, 0.f) + 1e-5f);
  float g4[4], b4[4];
  *(float4*)g4 = *(const float4*)(gam + i0);
  *(float4*)b4 = *(const float4*)(bet + i0);
  float sv[4]; float sss = 0.f;
  #pragma unroll
  for (int j = 0; j < 4; j++){
    sv[j] = (av[j] * rn - mu) * rv * g4[j] + b4[j];
    sss += sv[j] * sv[j];
  }
  sss = block_sum(sss, red);
  float tout = sqrtf(sss + 1.f);
  if (mode_out == 0){
    union { uint2 u; u16 h[4]; } o;
    #pragma unroll
    for (int j = 0; j < 4; j++) o.h[j] = f2bf(sv[j]);
    *(uint2*)(ob + (size_t)tok * 1024 + i0) = o.u;
    if (tid == 0) ot[tok] = tout;
  } else {
    float* orow = ofull + (size_t)tok * 1025;
    #pragma unroll
    for (int j = 0; j < 4; j++) orow[1 + i0 + j] = sv[j];
    if (tid == 0) orow[0] = tout;
  }
}

// ---------------------------------------------------------------- launch
extern "C" void kernel_launch(void* const* d_in, const int* in_sizes, int n_in,
                              void* d_out, int out_size, void* d_ws, size_t ws_size,
                              hipStream_t stream){
  const float* x   = (const float*)d_in[0];
  const float* Wq  = (const float*)d_in[1];
  const float* bq  = (const float*)d_in[2];
  const float* Wk  = (const float*)d_in[3];
  const float* bk  = (const float*)d_in[4];
  const float* Wv  = (const float*)d_in[5];
  const float* bv  = (const float*)d_in[6];
  const float* Wo  = (const float*)d_in[7];
  const float* bo  = (const float*)d_in[8];
  const float* g1  = (const float*)d_in[9];
  const float* be1 = (const float*)d_in[10];
  const float* W1  = (const float*)d_in[11];
  const float* c1  = (const float*)d_in[12];
  const float* W2  = (const float*)d_in[13];
  const float* c2  = (const float*)d_in[14];
  const float* g2  = (const float*)d_in[15];
  const float* be2 = (const float*)d_in[16];
  float* out = (float*)d_out;

  char* p = (char*)d_ws;
  auto take = [&](size_t n){ char* r = p; p += (n + 255) & ~(size_t)255; return r; };
  u16*   xs    = (u16*)  take((size_t)NTOK * 1024 * 2);
  float* xt    = (float*)take(NTOK * 4);
  u16*   wqkv  = (u16*)  take((size_t)3072 * 1024 * 2);
  float* wqkv0 = (float*)take(3072 * 4);
  u16*   wo_s  = (u16*)  take((size_t)1024 * 1024 * 2);
  float* wo0   = (float*)take(1024 * 4);
  u16*   w1_s  = (u16*)  take((size_t)4096 * 1024 * 2);
  float* w10   = (float*)take(4096 * 4);
  u16*   w2_s  = (u16*)  take((size_t)1024 * 4096 * 2);
  float* w20   = (float*)take(1024 * 4);
  u16*   qkvb  = (u16*)  take((size_t)NTOK * 3072 * 2);
  float* qtv   = (float*)take((size_t)64 * 1024 * 4);
  float* ktv   = (float*)take((size_t)64 * 1024 * 4);
  u16*   vT    = (u16*)  take((size_t)64 * 65 * 1024 * 2);
  u16*   aoutb = (u16*)  take((size_t)NTOK * 1024 * 2);
  float* sqbuf = (float*)take((size_t)2 * NTOK * 4);   // aot_sq | htv_sq (zeroed in conv_all)
  float* aot_sq = sqbuf;
  float* htv_sq = sqbuf + NTOK;
  u16*   zbuf  = (u16*)  take((size_t)4 * NTOK * 1024 * 2);   // up to 4 split-K bf16 slices
  u16*   x1b   = (u16*)  take((size_t)NTOK * 1024 * 2);
  float* x1t   = (float*)take(NTOK * 4);
  u16*   hbuf  = (u16*)  take((size_t)NTOK * 4096 * 2);

  // fused prologue: conv_x + conv_w_all + sqbuf zero (one launch)
  conv_all<<<4100 + 12297 + 32, 256, 0, stream>>>(
      x, Wq, Wk, Wv, Wo, W1, W2,
      xs, xt, wqkv, wo_s, w1_s, w2_s, wqkv0, wo0, w10, w20, sqbuf);

  // QKV + fused time norms + LDS-bounced transposed V write
  gemm128_qkv<<<dim3(24, 32), 256, 0, stream>>>(xs, wqkv, xt, wqkv0,
      bq, bk, bv, qkvb, qtv, ktv, vT);
  attn_kernel<<<dim3(8, 64), 512, 0, stream>>>(qkvb, qtv, ktv, vT, aoutb, aot_sq);
  // O-proj: split-K x2 (512 blocks), bf16 partial slices
  gemm128<<<dim3(8, 32, 2), 256, 0, stream>>>(aoutb, 1024, wo_s, 1024, aot_sq, 1, wo0,
      bo, zbuf, 1024, 512, 1, nullptr);
  mid_ln<<<NTOK, 256, 0, stream>>>(zbuf, xs, xt, g1, be1,
      x1b, x1t, nullptr, 0, 2);
  // MLP1 + relu + fused row sum-of-squares (M=4096, N=4096, K=1024) — 1024 blocks
  gemm128<<<dim3(32, 32), 256, 0, stream>>>(x1b, 1024, w1_s, 1024, x1t, 0, w10,
      c1, hbuf, 4096, 1024, 2, htv_sq);
  // MLP2: split-K x2 (512 blocks), Kslice 2048
  gemm128<<<dim3(8, 32, 2), 256, 0, stream>>>(hbuf, 4096, w2_s, 4096, htv_sq, 1, w20,
      c2, zbuf, 1024, 2048, 1, nullptr);
  mid_ln<<<NTOK, 256, 0, stream>>>(zbuf, x1b, x1t, g2, be2,
      nullptr, nullptr, out, 1, 2);
}

// Round 14
// 374.680 us; speedup vs baseline: 1.0309x; 1.0055x over previous
//
#include <hip/hip_runtime.h>

typedef unsigned short u16;
typedef unsigned int   u32;
typedef short bf16x8 __attribute__((ext_vector_type(8)));
typedef float f32x4  __attribute__((ext_vector_type(4)));

#define NTOK 4096   // B*S
#define SEQ  1024

__device__ __forceinline__ u16 f2bf(float f){
  union { float f; u32 u; } x; x.f = f;
  u32 r = (x.u + 0x7FFFu + ((x.u >> 16) & 1u)) >> 16;
  return (u16)r;
}
__device__ __forceinline__ float bf2f(u16 u){
  union { u32 u; float f; } x; x.u = ((u32)u) << 16; return x.f;
}
__device__ __forceinline__ void gl_lds16(const void* gp, void* lp){
  __builtin_amdgcn_global_load_lds(
      (const __attribute__((address_space(1))) u32*)gp,
      (__attribute__((address_space(3))) u32*)lp, 16, 0, 0);
}

// ---------------------------------------------------------------- fused prologue
// One launch: conv_x + conv_w_all + sqbuf zero. Region boundaries block-aligned.
__global__ __launch_bounds__(256) void conv_all(
    const float* __restrict__ x,
    const float* __restrict__ Wq, const float* __restrict__ Wk,
    const float* __restrict__ Wv, const float* __restrict__ Wo,
    const float* __restrict__ W1, const float* __restrict__ W2,
    u16* __restrict__ xs, float* __restrict__ xt,
    u16* __restrict__ wqkv, u16* __restrict__ wo_s, u16* __restrict__ w1_s, u16* __restrict__ w2_s,
    float* __restrict__ wqkv0, float* __restrict__ wo0, float* __restrict__ w10, float* __restrict__ w20,
    float* __restrict__ sqbuf)
{
  int t = blockIdx.x * 256 + threadIdx.x;
  const int QX = 1049600;                 // x quads (4100 blocks)
  const int Q1 = 262400;                  // quads per 1024x1025 weight
  const int QW = 4 * Q1 + 1049600 + 1048832;   // 3,148,032 (12297 blocks)
  if (t < QX){
    int e = t * 4;
    int r = (u32)e / 1025u;
    int c = e - r * 1025;
    float4 v = *(const float4*)(x + (size_t)e);
    const float* vp = (const float*)&v;
    #pragma unroll
    for (int k = 0; k < 4; k++){
      if (c == 0) xt[r] = vp[k];
      else xs[(size_t)r * 1024 + (c - 1)] = f2bf(vp[k]);
      if (++c == 1025){ c = 0; ++r; }
    }
    return;
  }
  t -= QX;
  if (t < QW){
    const float* W; u16* Wb; float* w0; int divr, Kin, e;
    if (t < 4 * Q1){
      int region = t / Q1; int qq = t - region * Q1;
      e = qq * 4; divr = 1025; Kin = 1024;
      if (region == 0)      { W = Wq; Wb = wqkv;             w0 = wqkv0; }
      else if (region == 1) { W = Wk; Wb = wqkv + (1 << 20); w0 = wqkv0 + 1024; }
      else if (region == 2) { W = Wv; Wb = wqkv + (2 << 20); w0 = wqkv0 + 2048; }
      else                  { W = Wo; Wb = wo_s;             w0 = wo0; }
    } else if (t < 4 * Q1 + 1049600){
      e = (t - 4 * Q1) * 4; divr = 1025; Kin = 1024; W = W1; Wb = w1_s; w0 = w10;
    } else {
      e = (t - 4 * Q1 - 1049600) * 4; divr = 4097; Kin = 4096; W = W2; Wb = w2_s; w0 = w20;
    }
    int r = (divr == 1025) ? (int)((u32)e / 1025u) : (int)((u32)e / 4097u);
    int c = e - r * divr;
    float4 v = *(const float4*)(W + (size_t)e);
    const float* vp = (const float*)&v;
    #pragma unroll
    for (int k = 0; k < 4; k++){
      if (c == 0) w0[r] = vp[k];
      else Wb[(size_t)r * Kin + (c - 1)] = f2bf(vp[k]);
      if (++c == divr){ c = 0; ++r; }
    }
    return;
  }
  t -= QW;
  if (t < 2 * NTOK) sqbuf[t] = 0.f;       // aot_sq | htv_sq zero (32 blocks)
}

// ---------------------------------------------------------------- QKV GEMM (isolated, mode-0; V written transposed)
// Q/K blocks (n0 < 2048): qkvb + qtv/ktv time rows.
// V blocks (n0 >= 2048): transpose through dead As/Bs staging LDS (two
// [64][136] feature-major tiles), then 2048 coalesced 16B chunk writes to vT.
__global__ __launch_bounds__(256) void gemm128_qkv(
    const u16* __restrict__ A, const u16* __restrict__ Bm,
    const float* __restrict__ at, const float* __restrict__ b0,
    const float* __restrict__ bias_a, const float* __restrict__ bias_b, const float* __restrict__ bias_c,
    u16* __restrict__ Cbf,
    float* __restrict__ qtv, float* __restrict__ ktv, u16* __restrict__ vT)
{
  __shared__ u16 As[2][128 * 64];
  __shared__ u16 Bs[2][128 * 64];
  const int tid = threadIdx.x;
  const int w = tid >> 6, l = tid & 63;
  const int l15 = l & 15, q = l >> 4;
  const int m0 = blockIdx.y * 128, n0 = blockIdx.x * 128;
  const int wr = w >> 1, wc = w & 1;
  f32x4 acc[4][4] = {};

  auto stage = [&](int kt, int buf){
    #pragma unroll
    for (int half = 0; half < 2; half++){
      #pragma unroll
      for (int i = 0; i < 2; i++){
        int s = (w * 2 + i) * 64 + l;
        int row = s >> 2;
        int kc = ((s & 3) - (s >> 3)) & 3;
        gl_lds16(A  + (size_t)(m0 + row) * 1024 + kt + half * 32 + kc * 8,
                 &As[buf][half * 4096 + (w * 2 + i) * 512]);
        gl_lds16(Bm + (size_t)(n0 + row) * 1024 + kt + half * 32 + kc * 8,
                 &Bs[buf][half * 4096 + (w * 2 + i) * 512]);
      }
    }
  };
  auto compute = [&](int buf, int half){
    bf16x8 af[4], bfr[4];
    #pragma unroll
    for (int i = 0; i < 4; i++){
      int row = wr * 64 + i * 16 + l15;
      int slot = row * 4 + ((q + (row >> 1)) & 3);
      af[i] = *(const bf16x8*)&As[buf][half * 4096 + slot * 8];
    }
    #pragma unroll
    for (int j = 0; j < 4; j++){
      int row = wc * 64 + j * 16 + l15;
      int slot = row * 4 + ((q + (row >> 1)) & 3);
      bfr[j] = *(const bf16x8*)&Bs[buf][half * 4096 + slot * 8];
    }
    #pragma unroll
    for (int i = 0; i < 4; i++)
      #pragma unroll
      for (int j = 0; j < 4; j++)
        acc[i][j] = __builtin_amdgcn_mfma_f32_16x16x32_bf16(af[i], bfr[j], acc[i][j], 0, 0, 0);
  };

  stage(0, 0);
  for (int kt = 0; kt < 1024; kt += 128){
    __syncthreads();
    if (kt + 64 < 1024) stage(kt + 64, 1);
    compute(0, 0); compute(0, 1);
    __syncthreads();
    if (kt + 128 < 1024) stage(kt + 128, 0);
    compute(1, 0); compute(1, 1);
  }

  const bool isV = (n0 >= 2048);          // block-uniform
  if (!isV){
    #pragma unroll
    for (int i = 0; i < 4; i++){
      const int row0 = m0 + wr * 64 + i * 16 + q * 4;   // 4 consecutive tokens
      float atv[4];
      #pragma unroll
      for (int r = 0; r < 4; r++) atv[r] = at[row0 + r];
      float p[4] = {0.f, 0.f, 0.f, 0.f};
      #pragma unroll
      for (int j = 0; j < 4; j++){
        int col = n0 + wc * 64 + j * 16 + l15;
        float b0v = b0[col];
        float bv = (col < 1024) ? bias_a[col] : bias_b[col - 1024];
        #pragma unroll
        for (int r = 0; r < 4; r++){
          float vv = acc[i][j][r] + atv[r] * b0v + bv;
          p[r] += vv * vv;
          Cbf[(size_t)(row0 + r) * 3072 + col] = f2bf(vv);
        }
      }
      #pragma unroll
      for (int r = 0; r < 4; r++){
        float s = p[r];
        s += __shfl_xor(s, 1, 64); s += __shfl_xor(s, 2, 64);
        s += __shfl_xor(s, 4, 64); s += __shfl_xor(s, 8, 64);
        if (l15 == 0){
          int row = row0 + r;
          int ch = (n0 + wc * 64) >> 6;       // 0..31
          int bb = row >> 10, sidx = row & 1023;
          float t = sqrtf(s + 1.f);
          if (ch < 16) qtv[((size_t)bb * 16 + ch) * 1024 + sidx] = t;
          else         ktv[((size_t)bb * 16 + ch - 16) * 1024 + sidx] = t;
        }
      }
    }
  } else {
    // ---- V: transpose through LDS scratch, then coalesced 16B writes
    u16* scr0 = (u16*)As;                 // features 0..63   [64][136]
    u16* scr1 = (u16*)Bs;                 // features 64..127 [64][136]
    __syncthreads();                      // all K-loop LDS reads done
    #pragma unroll
    for (int i = 0; i < 4; i++){
      const int tloc0 = wr * 64 + i * 16 + q * 4;       // 4 consecutive local tokens
      const int row0 = m0 + tloc0;
      float atv[4];
      #pragma unroll
      for (int r = 0; r < 4; r++) atv[r] = at[row0 + r];
      float p[4] = {0.f, 0.f, 0.f, 0.f};
      u16* scr = wc ? scr1 : scr0;
      #pragma unroll
      for (int j = 0; j < 4; j++){
        int col = n0 + wc * 64 + j * 16 + l15;
        float b0v = b0[col];
        float bv = bias_c[col - 2048];
        union { uint2 u; u16 h[4]; } o;
        #pragma unroll
        for (int r = 0; r < 4; r++){
          float vv = acc[i][j][r] + atv[r] * b0v + bv;
          p[r] += vv * vv;
          o.h[r] = f2bf(vv);
        }
        *(uint2*)&scr[(j * 16 + l15) * 136 + tloc0] = o.u;
      }
      #pragma unroll
      for (int r = 0; r < 4; r++){
        float s = p[r];
        s += __shfl_xor(s, 1, 64); s += __shfl_xor(s, 2, 64);
        s += __shfl_xor(s, 4, 64); s += __shfl_xor(s, 8, 64);
        if (l15 == 0){
          int row = row0 + r;
          int ch = (n0 + wc * 64) >> 6;       // 32..47
          int bb = row >> 10, sidx = row & 1023;
          vT[((size_t)(bb * 16 + ch - 32) * 65) * 1024 + sidx] = f2bf(sqrtf(s + 1.f));
        }
      }
    }
    __syncthreads();                      // scratch complete
    const int hvbase = (n0 - 2048) >> 6;
    const int bb = m0 >> 10, sbase = m0 & 1023;
    for (int c = tid; c < 2048; c += 256){
      int f = c >> 4, tc = c & 15;        // feature 0..127, token-chunk 0..15
      const u16* scr = (f < 64) ? scr0 : scr1;
      uint4 d = *(const uint4*)&scr[(f & 63) * 136 + tc * 8];
      int hv = hvbase + (f >> 6), fl = f & 63;
      *(uint4*)(vT + ((size_t)(bb * 16 + hv) * 65 + 1 + fl) * 1024 + sbase + tc * 8) = d;
    }
  }
}

// ---------------------------------------------------------------- generic GEMM 128x128 (modes 1/2)
__global__ __launch_bounds__(256) void gemm128(
    const u16* __restrict__ A, int lda, const u16* __restrict__ Bm, int ldb,
    const float* __restrict__ at, int at_mode, const float* __restrict__ b0,
    const float* __restrict__ bias_a,
    u16* __restrict__ Cbf, int ldc, int Kslice, int mode,
    float* __restrict__ rowsq)
{
  __shared__ u16 As[2][128 * 64];
  __shared__ u16 Bs[2][128 * 64];
  const int tid = threadIdx.x;
  const int w = tid >> 6, l = tid & 63;
  const int l15 = l & 15, q = l >> 4;
  const int m0 = blockIdx.y * 128, n0 = blockIdx.x * 128;
  const int ks = blockIdx.z;
  const int kbeg = ks * Kslice;
  const int kend = kbeg + Kslice;
  const int wr = w >> 1, wc = w & 1;
  f32x4 acc[4][4] = {};

  auto stage = [&](int kt, int buf){
    #pragma unroll
    for (int half = 0; half < 2; half++){
      #pragma unroll
      for (int i = 0; i < 2; i++){
        int s = (w * 2 + i) * 64 + l;
        int row = s >> 2;
        int kc = ((s & 3) - (s >> 3)) & 3;
        gl_lds16(A  + (size_t)(m0 + row) * lda + kt + half * 32 + kc * 8,
                 &As[buf][half * 4096 + (w * 2 + i) * 512]);
        gl_lds16(Bm + (size_t)(n0 + row) * ldb + kt + half * 32 + kc * 8,
                 &Bs[buf][half * 4096 + (w * 2 + i) * 512]);
      }
    }
  };
  auto compute = [&](int buf, int half){
    bf16x8 af[4], bfr[4];
    #pragma unroll
    for (int i = 0; i < 4; i++){
      int row = wr * 64 + i * 16 + l15;
      int slot = row * 4 + ((q + (row >> 1)) & 3);
      af[i] = *(const bf16x8*)&As[buf][half * 4096 + slot * 8];
    }
    #pragma unroll
    for (int j = 0; j < 4; j++){
      int row = wc * 64 + j * 16 + l15;
      int slot = row * 4 + ((q + (row >> 1)) & 3);
      bfr[j] = *(const bf16x8*)&Bs[buf][half * 4096 + slot * 8];
    }
    #pragma unroll
    for (int i = 0; i < 4; i++)
      #pragma unroll
      for (int j = 0; j < 4; j++)
        acc[i][j] = __builtin_amdgcn_mfma_f32_16x16x32_bf16(af[i], bfr[j], acc[i][j], 0, 0, 0);
  };

  stage(kbeg, 0);
  for (int kt = kbeg; kt < kend; kt += 128){
    __syncthreads();
    if (kt + 64 < kend) stage(kt + 64, 1);
    compute(0, 0); compute(0, 1);
    __syncthreads();
    if (kt + 128 < kend) stage(kt + 128, 0);
    compute(1, 0); compute(1, 1);
  }

  const size_t slice_off = (size_t)ks * (size_t)(gridDim.y * 128) * ldc;
  #pragma unroll
  for (int i = 0; i < 4; i++){
    float atv[4];
    #pragma unroll
    for (int r = 0; r < 4; r++){
      float a = at[m0 + wr * 64 + i * 16 + q * 4 + r];
      atv[r] = at_mode ? sqrtf(a + 1.f) : a;
    }
    float p[4] = {0.f, 0.f, 0.f, 0.f};
    #pragma unroll
    for (int j = 0; j < 4; j++){
      int col = n0 + wc * 64 + j * 16 + l15;
      float b0v = b0[col];
      float bv = bias_a[col];
      #pragma unroll
      for (int r = 0; r < 4; r++){
        size_t row = (size_t)(m0 + wr * 64 + i * 16 + q * 4 + r);
        float add = (ks == 0) ? (atv[r] * b0v + bv) : 0.f;
        float v = acc[i][j][r] + add;
        if (mode == 2) v = fmaxf(v, 0.f);
        Cbf[slice_off + row * ldc + col] = f2bf(v);
        if (mode == 2) p[r] += v * v;
      }
    }
    if (mode == 2){
      #pragma unroll
      for (int r = 0; r < 4; r++){
        float s = p[r];
        s += __shfl_xor(s, 1, 64); s += __shfl_xor(s, 2, 64);
        s += __shfl_xor(s, 4, 64); s += __shfl_xor(s, 8, 64);
        if (l15 == 0) atomicAdd(&rowsq[m0 + wr * 64 + i * 16 + q * 4 + r], s);
      }
    }
  }
}

// ---------------------------------------------------------------- flash attention
// Round-14 changes (attn-only): (1) T13 defer-max THR=8 — skip the acco
// rescale (and its exp on the critical path) when the tile max doesn't
// exceed the running max by >8; P bounded by e^8, bf16/f32 tolerate.
// (2) ktm row prefetched per tile before the QK MFMA cluster (hides L2
// latency under 8 MFMAs). (3) dropped the manual lgkmcnt(0) full drain
// before P reads — compiler inserts a precisely-counted wait (it sees the
// Plds aliasing).
__global__ __launch_bounds__(512) void attn_kernel(
    const u16* __restrict__ qkv, const float* __restrict__ qt,
    const float* __restrict__ ktm, const u16* __restrict__ vT,
    u16* __restrict__ aout, float* __restrict__ aot_sq)
{
  __shared__ u16 smem[30720];   // 61440 B
  u16* Qlds = smem;                                   // [0,8192) prologue only
  u16* Kl0 = smem + 8192;                             // [8192,12288)
  u16* Kl1 = smem + 12288;                            // [12288,16384)
  u16* Vl0 = smem + 16384;                            // [16384,21504) 5120
  u16* Vl1 = smem;                                    // reuse Q region (5120)
  u16* Plds = smem + 21504;                           // [21504,30720) 9216
  const int tid = threadIdx.x;
  const int w = tid >> 6, l = tid & 63;
  const int l15 = l & 15, qd = l >> 4;
  const int q0 = blockIdx.x * 128;
  const int bh = blockIdx.y;
  const int b = bh >> 4, h = bh & 15;
  const size_t tokbase = (size_t)b << 10;

  #pragma unroll
  for (int i = 0; i < 2; i++){
    int c = i * 512 + w * 64 + l;                 // chunk slot 0..1023
    int row = c >> 3, kc = ((c & 7) - row) & 7;   // slot = row*8+((kc+row)&7)
    gl_lds16(qkv + (tokbase + q0 + row) * 3072 + h * 64 + kc * 8, &Qlds[(i * 512 + w * 64) * 8]);
  }
  __syncthreads();
  bf16x8 aq[2];
  {
    int row = w * 16 + l15;
    #pragma unroll
    for (int kk = 0; kk < 2; kk++)
      aq[kk] = *(const bf16x8*)&Qlds[(row * 8 + ((kk * 4 + qd + row) & 7)) * 8];
  }
  float tq[4];
  #pragma unroll
  for (int r = 0; r < 4; r++)
    tq[r] = qt[(size_t)bh * SEQ + q0 + w * 16 + qd * 4 + r];

  auto stage_kv = [&](int kt, int buf){
    u16* K = buf ? Kl1 : Kl0;
    u16* V = buf ? Vl1 : Vl0;
    int c = w * 64 + l;                           // 512 chunks
    int row = c >> 3, kc = ((c & 7) - row) & 7;
    gl_lds16(qkv + (tokbase + kt * 64 + row) * 3072 + 1024 + h * 64 + kc * 8, &K[w * 512]);
    gl_lds16(vT + ((size_t)bh * 65 + row) * 1024 + kt * 64 + kc * 8, &V[w * 512]);
    if (w == 0 && l < 8)                          // vT row 64: slots 512..519
      gl_lds16(vT + ((size_t)bh * 65 + 64) * 1024 + kt * 64 + (l & 7) * 8, &V[4096]);
  };

  float mrow[4] = {-1e30f, -1e30f, -1e30f, -1e30f};
  f32x4 acco[5] = {};

  stage_kv(0, 0);                                 // Q region untouched here
  for (int kt = 0; kt < 16; kt++){
    __syncthreads();    // buf(kt&1) K/V resident; (kt=0) all aq reads drained
    if (kt + 1 < 16) stage_kv(kt + 1, (kt + 1) & 1);
    u16* K = (kt & 1) ? Kl1 : Kl0;
    u16* V = (kt & 1) ? Vl1 : Vl0;

    // prefetch tile's ktm row (4 loads in flight across the MFMA cluster)
    float tk4[4];
    #pragma unroll
    for (int ct = 0; ct < 4; ct++)
      tk4[ct] = ktm[(size_t)bh * SEQ + kt * 64 + ct * 16 + l15];

    float sc[4][4];
    float mx[4] = {-1e30f, -1e30f, -1e30f, -1e30f};
    #pragma unroll
    for (int ct = 0; ct < 4; ct++){
      f32x4 z = {0.f, 0.f, 0.f, 0.f};
      int key = ct * 16 + l15;
      __builtin_amdgcn_s_setprio(1);
      #pragma unroll
      for (int kk = 0; kk < 2; kk++){
        bf16x8 bk = *(const bf16x8*)&K[(key * 8 + ((kk * 4 + qd + key) & 7)) * 8];
        z = __builtin_amdgcn_mfma_f32_16x16x32_bf16(aq[kk], bk, z, 0, 0, 0);
      }
      __builtin_amdgcn_s_setprio(0);
      #pragma unroll
      for (int r = 0; r < 4; r++){
        float s = 0.25f + 0.25f * (z[r] - tq[r] * tk4[ct]);
        sc[ct][r] = s;
        mx[r] = fmaxf(mx[r], s);
      }
    }
    #pragma unroll
    for (int r = 0; r < 4; r++){
      #pragma unroll
      for (int msk = 1; msk < 16; msk <<= 1)
        mx[r] = fmaxf(mx[r], __shfl_xor(mx[r], msk, 64));
      // defer-max (T13): only rescale when tile max exceeds running max by >8
      if (mx[r] > mrow[r] + 8.f){
        float mnew = mx[r];
        float alpha = __expf(mrow[r] - mnew);
        mrow[r] = mnew;
        #pragma unroll
        for (int co = 0; co < 5; co++) acco[co][r] *= alpha;
      }
    }
    #pragma unroll
    for (int ct = 0; ct < 4; ct++)
      #pragma unroll
      for (int r = 0; r < 4; r++)
        Plds[w * 1152 + (qd * 4 + r) * 72 + ct * 16 + l15] = f2bf(__expf(sc[ct][r] - mrow[r]));
    bf16x8 ap[2];
    #pragma unroll
    for (int kk = 0; kk < 2; kk++)
      ap[kk] = *(const bf16x8*)&Plds[w * 1152 + l15 * 72 + kk * 32 + qd * 8];
    __builtin_amdgcn_s_setprio(1);
    #pragma unroll
    for (int co = 0; co < 5; co++){
      int vtr = co * 16 + l15;
      #pragma unroll
      for (int kk = 0; kk < 2; kk++){
        bf16x8 bv = *(const bf16x8*)&V[(vtr * 8 + ((kk * 4 + qd + vtr) & 7)) * 8];
        acco[co] = __builtin_amdgcn_mfma_f32_16x16x32_bf16(ap[kk], bv, acco[co], 0, 0, 0);
      }
    }
    __builtin_amdgcn_s_setprio(0);
  }
  #pragma unroll
  for (int r = 0; r < 4; r++){
    float ss = 0.f;
    #pragma unroll
    for (int co = 0; co < 5; co++){
      int col = co * 16 + l15;
      float v = acco[co][r];
      if (col == 0) ss -= v * v;
      else if (col < 65) ss += v * v;
    }
    #pragma unroll
    for (int msk = 1; msk < 16; msk <<= 1) ss += __shfl_xor(ss, msk, 64);
    float v0b = __shfl(acco[0][r], l & 48, 64);       // time comp broadcast in 16-group
    float sp = ss + v0b * v0b;                        // sum of space^2
    float rn = rsqrtf(fmaxf(fabsf(ss), 1e-8f));
    size_t rowg = tokbase + q0 + w * 16 + qd * 4 + r;
    if (l15 == 0) atomicAdd(&aot_sq[rowg], sp * rn * rn);
    #pragma unroll
    for (int co = 0; co < 5; co++){
      int col = co * 16 + l15;
      if (col >= 1 && col < 65)
        aout[rowg * 1024 + h * 64 + col - 1] = f2bf(acco[co][r] * rn);
    }
  }
}

// ---------------------------------------------------------------- midpoint + hyp_layernorm
__device__ __forceinline__ void block_sum3(float& a, float& b, float& c, float* red){
  int tid = threadIdx.x;
  #pragma unroll
  for (int m = 1; m < 64; m <<= 1){
    a += __shfl_xor(a, m, 64);
    b += __shfl_xor(b, m, 64);
    c += __shfl_xor(c, m, 64);
  }
  __syncthreads();
  if ((tid & 63) == 0){ int w = tid >> 6; red[w] = a; red[4 + w] = b; red[8 + w] = c; }
  __syncthreads();
  a = red[0] + red[1] + red[2] + red[3];
  b = red[4] + red[5] + red[6] + red[7];
  c = red[8] + red[9] + red[10] + red[11];
}
__device__ __forceinline__ float block_sum(float v, float* red){
  int tid = threadIdx.x;
  #pragma unroll
  for (int m = 1; m < 64; m <<= 1) v += __shfl_xor(v, m, 64);
  __syncthreads();
  if ((tid & 63) == 0) red[tid >> 6] = v;
  __syncthreads();
  return red[0] + red[1] + red[2] + red[3];
}

__global__ __launch_bounds__(256) void mid_ln(
    const u16* __restrict__ z, const u16* __restrict__ xsb, const float* __restrict__ xtv,
    const float* __restrict__ gam, const float* __restrict__ bet,
    u16* __restrict__ ob, float* __restrict__ ot,
    float* __restrict__ ofull, int mode_out, int nsl)
{
  __shared__ float red[12];
  const int tid = threadIdx.x;
  const int tok = blockIdx.x;
  const int i0 = tid * 4;
  float zv[4], xv[4], av[4];
  float xtime = xtv[tok];
  {
    union { uint2 u; u16 h[4]; } xu;
    xu.u = *(const uint2*)(xsb + (size_t)tok * 1024 + i0);
    #pragma unroll
    for (int j = 0; j < 4; j++) xv[j] = bf2f(xu.h[j]);
  }
  #pragma unroll
  for (int j = 0; j < 4; j++) zv[j] = 0.f;
  for (int s = 0; s < nsl; s++){
    union { uint2 u; u16 h[4]; } zu;
    zu.u = *(const uint2*)(z + (size_t)s * NTOK * 1024 + (size_t)tok * 1024 + i0);
    #pragma unroll
    for (int j = 0; j < 4; j++) zv[j] += bf2f(zu.h[j]);
  }
  float ssz = 0.f, ssa = 0.f, sa = 0.f;
  #pragma unroll
  for (int j = 0; j < 4; j++){
    ssz += zv[j] * zv[j];
    av[j] = 0.5f * (zv[j] + xv[j]);
    ssa += av[j] * av[j];
    sa += av[j];
  }
  block_sum3(ssz, ssa, sa, red);
  float tz = sqrtf(ssz + 1.f);
  float avt = 0.5f * (tz + xtime);
  float rn = rsqrtf(fmaxf(fabsf(ssa - avt * avt), 1e-8f));
  float mu = sa * rn * (1.f / 1024.f);
  float squ = ssa * rn * rn;
  float var = squ * (1.f / 1024.f) - mu * mu;
  float rv = rsqrtf(fmaxf(var, 0.f) + 1e-5f);
  float g4[4], b4[4];
  *(float4*)g4 = *(const float4*)(gam + i0);
  *(float4*)b4 = *(const float4*)(bet + i0);
  float sv[4]; float sss = 0.f;
  #pragma unroll
  for (int j = 0; j < 4; j++){
    sv[j] = (av[j] * rn - mu) * rv * g4[j] + b4[j];
    sss += sv[j] * sv[j];
  }
  sss = block_sum(sss, red);
  float tout = sqrtf(sss + 1.f);
  if (mode_out == 0){
    union { uint2 u; u16 h[4]; } o;
    #pragma unroll
    for (int j = 0; j < 4; j++) o.h[j] = f2bf(sv[j]);
    *(uint2*)(ob + (size_t)tok * 1024 + i0) = o.u;
    if (tid == 0) ot[tok] = tout;
  } else {
    float* orow = ofull + (size_t)tok * 1025;
    #pragma unroll
    for (int j = 0; j < 4; j++) orow[1 + i0 + j] = sv[j];
    if (tid == 0) orow[0] = tout;
  }
}

// ---------------------------------------------------------------- launch
extern "C" void kernel_launch(void* const* d_in, const int* in_sizes, int n_in,
                              void* d_out, int out_size, void* d_ws, size_t ws_size,
                              hipStream_t stream){
  const float* x   = (const float*)d_in[0];
  const float* Wq  = (const float*)d_in[1];
  const float* bq  = (const float*)d_in[2];
  const float* Wk  = (const float*)d_in[3];
  const float* bk  = (const float*)d_in[4];
  const float* Wv  = (const float*)d_in[5];
  const float* bv  = (const float*)d_in[6];
  const float* Wo  = (const float*)d_in[7];
  const float* bo  = (const float*)d_in[8];
  const float* g1  = (const float*)d_in[9];
  const float* be1 = (const float*)d_in[10];
  const float* W1  = (const float*)d_in[11];
  const float* c1  = (const float*)d_in[12];
  const float* W2  = (const float*)d_in[13];
  const float* c2  = (const float*)d_in[14];
  const float* g2  = (const float*)d_in[15];
  const float* be2 = (const float*)d_in[16];
  float* out = (float*)d_out;

  char* p = (char*)d_ws;
  auto take = [&](size_t n){ char* r = p; p += (n + 255) & ~(size_t)255; return r; };
  u16*   xs    = (u16*)  take((size_t)NTOK * 1024 * 2);
  float* xt    = (float*)take(NTOK * 4);
  u16*   wqkv  = (u16*)  take((size_t)3072 * 1024 * 2);
  float* wqkv0 = (float*)take(3072 * 4);
  u16*   wo_s  = (u16*)  take((size_t)1024 * 1024 * 2);
  float* wo0   = (float*)take(1024 * 4);
  u16*   w1_s  = (u16*)  take((size_t)4096 * 1024 * 2);
  float* w10   = (float*)take(4096 * 4);
  u16*   w2_s  = (u16*)  take((size_t)1024 * 4096 * 2);
  float* w20   = (float*)take(1024 * 4);
  u16*   qkvb  = (u16*)  take((size_t)NTOK * 3072 * 2);
  float* qtv   = (float*)take((size_t)64 * 1024 * 4);
  float* ktv   = (float*)take((size_t)64 * 1024 * 4);
  u16*   vT    = (u16*)  take((size_t)64 * 65 * 1024 * 2);
  u16*   aoutb = (u16*)  take((size_t)NTOK * 1024 * 2);
  float* sqbuf = (float*)take((size_t)2 * NTOK * 4);   // aot_sq | htv_sq (zeroed in conv_all)
  float* aot_sq = sqbuf;
  float* htv_sq = sqbuf + NTOK;
  u16*   zbuf  = (u16*)  take((size_t)4 * NTOK * 1024 * 2);   // up to 4 split-K bf16 slices
  u16*   x1b   = (u16*)  take((size_t)NTOK * 1024 * 2);
  float* x1t   = (float*)take(NTOK * 4);
  u16*   hbuf  = (u16*)  take((size_t)NTOK * 4096 * 2);

  // fused prologue: conv_x + conv_w_all + sqbuf zero (one launch)
  conv_all<<<4100 + 12297 + 32, 256, 0, stream>>>(
      x, Wq, Wk, Wv, Wo, W1, W2,
      xs, xt, wqkv, wo_s, w1_s, w2_s, wqkv0, wo0, w10, w20, sqbuf);

  // QKV + fused time norms + LDS-bounced transposed V write
  gemm128_qkv<<<dim3(24, 32), 256, 0, stream>>>(xs, wqkv, xt, wqkv0,
      bq, bk, bv, qkvb, qtv, ktv, vT);
  attn_kernel<<<dim3(8, 64), 512, 0, stream>>>(qkvb, qtv, ktv, vT, aoutb, aot_sq);
  // O-proj: split-K x2 (512 blocks), bf16 partial slices
  gemm128<<<dim3(8, 32, 2), 256, 0, stream>>>(aoutb, 1024, wo_s, 1024, aot_sq, 1, wo0,
      bo, zbuf, 1024, 512, 1, nullptr);
  mid_ln<<<NTOK, 256, 0, stream>>>(zbuf, xs, xt, g1, be1,
      x1b, x1t, nullptr, 0, 2);
  // MLP1 + relu + fused row sum-of-squares (M=4096, N=4096, K=1024) — 1024 blocks
  gemm128<<<dim3(32, 32), 256, 0, stream>>>(x1b, 1024, w1_s, 1024, x1t, 0, w10,
      c1, hbuf, 4096, 1024, 2, htv_sq);
  // MLP2: split-K x2 (512 blocks), Kslice 2048
  gemm128<<<dim3(8, 32, 2), 256, 0, stream>>>(hbuf, 4096, w2_s, 4096, htv_sq, 1, w20,
      c2, zbuf, 1024, 2048, 1, nullptr);
  mid_ln<<<NTOK, 256, 0, stream>>>(zbuf, x1b, x1t, g2, be2,
      nullptr, nullptr, out, 1, 2);
}